// Round 16
// baseline (73.627 us; speedup 1.0000x reference)
//
#include <hip/hip_runtime.h>

typedef __attribute__((ext_vector_type(8))) short short8v;
typedef __attribute__((ext_vector_type(16))) float f32x16;

#define BATCH 128
#define CIN 8
#define HW 128
#define COUT 64
#define OHW 126
#define NG 16
#define PH 31
#define GN_EPS 1e-5f

#define ROWS_A 8
#define STRIPS_A 16
#define INROWS_A 11   // 10 real + 1 zero pad (kk=1,h=1 reads; zero weights there)
#define ACOLS 132

static __device__ __forceinline__ unsigned short f2bf(float f) {
    unsigned u = __float_as_uint(f);
    return (unsigned short)((u + 0x7fffu + ((u >> 16) & 1u)) >> 16);
}
static __device__ __forceinline__ unsigned pk2(float a, float b) {
    return (unsigned)f2bf(a) | ((unsigned)f2bf(b) << 16);
}

// ---- pass A: 32x32x16 bf16-MFMA conv ONCE (r15 proven hot loop, byte-identical).
//      prep_weights merged into the prologue: each lane builds its 12 B-frags
//      directly from w (L1/L2-hot), overlapping the staging loads. ----
__global__ __launch_bounds__(256, 4) void conv_fused(
    const float* __restrict__ x, const float* __restrict__ w,
    const float* __restrict__ bias, const float* __restrict__ gnw,
    const float* __restrict__ scale, float* __restrict__ part,
    float* __restrict__ mzbuf)
{
    __shared__ __align__(16) short Abuf[INROWS_A][ACOLS][8];
    __shared__ float red[4][NG][2];
    const int strip = blockIdx.x, b = blockIdx.y;
    const int tid = threadIdx.x, wave = tid >> 6, lane = tid & 63;
    const int h = lane >> 5, m31 = lane & 31;
    const int r0 = strip * ROWS_A;

    // staging — round-2/11 verbatim (issue first; B-frag build overlaps the latency)
    {
        const float* xb = x + (size_t)b * CIN * HW * HW;
        for (int e = tid; e < INROWS_A * ACOLS; e += 256) {
            int row = e / ACOLS, col = e % ACOLS;
            int ri = r0 + row;
            bool ok = (row < 10) && (ri < HW) && (col < HW);
            unsigned pk0, pk1, pk2_, pk3;
            {
                const float* base = &xb[(size_t)ri * HW + col];
                float v0 = ok ? base[0 * HW * HW] : 0.f;
                float v1 = ok ? base[1 * HW * HW] : 0.f;
                float v2 = ok ? base[2 * HW * HW] : 0.f;
                float v3 = ok ? base[3 * HW * HW] : 0.f;
                float v4 = ok ? base[4 * HW * HW] : 0.f;
                float v5 = ok ? base[5 * HW * HW] : 0.f;
                float v6 = ok ? base[6 * HW * HW] : 0.f;
                float v7 = ok ? base[7 * HW * HW] : 0.f;
                pk0  = pk2(v0, v1);
                pk1  = pk2(v2, v3);
                pk2_ = pk2(v4, v5);
                pk3  = pk2(v6, v7);
            }
            uint4 w4 = make_uint4(pk0, pk1, pk2_, pk3);
            *(uint4*)&Abuf[row][col][0] = w4;
        }
    }

    // B fragments built in-register from w (former prep_weights, same layout/math):
    // frag (dx,kk,nt): n = nt*32+m31, dy = kk*2+h, elem j: w[((n*8+j)*3+dy)*3+dx] * sgn_n
    short8v bq[3][2][2];
    float sgn[2], bs2[2], bsg[2];
    #pragma unroll
    for (int nt = 0; nt < 2; ++nt) {
        const int n = nt * 32 + m31;
        const float bc = bias[n];
        const float sg = copysignf(1.f, gnw[n] * scale[n]);
        sgn[nt] = sg;
        bs2[nt] = 2.f * bc;
        bsg[nt] = sg * bc;
        #pragma unroll
        for (int kk = 0; kk < 2; ++kk) {
            const int dy = kk * 2 + h;
            #pragma unroll
            for (int dx = 0; dx < 3; ++dx) {
                unsigned p0, p1, p2, p3;
                if (dy < 3) {
                    const float* wb = &w[((size_t)n * CIN * 3 + dy) * 3 + dx];
                    float u0 = wb[0]  * sg, u1 = wb[9]  * sg;
                    float u2 = wb[18] * sg, u3 = wb[27] * sg;
                    float u4 = wb[36] * sg, u5 = wb[45] * sg;
                    float u6 = wb[54] * sg, u7 = wb[63] * sg;
                    p0 = pk2(u0, u1); p1 = pk2(u2, u3);
                    p2 = pk2(u4, u5); p3 = pk2(u6, u7);
                } else {
                    p0 = p1 = p2 = p3 = 0u;
                }
                uint4 u = make_uint4(p0, p1, p2, p3);
                bq[dx][kk][nt] = *(short8v*)&u;
            }
        }
    }
    __syncthreads();

    float s1[2] = {0.f, 0.f}, s2[2] = {0.f, 0.f};
    const int myprow = wave & 1;        // pool row within strip
    const int thalf  = wave >> 1;       // col-tile half
    const int prow_g = strip * 2 + myprow;

    for (int tt = 0; tt < 2; ++tt) {
        const int t32 = thalf * 2 + tt;           // 32-col tile 0..3
        const int colbase = 32 * t32 + m31;
        float mzw[2][4];
        #pragma unroll
        for (int nt = 0; nt < 2; ++nt)
            #pragma unroll
            for (int q = 0; q < 4; ++q) mzw[nt][q] = -3e38f;

        #pragma unroll
        for (int ri_ = 0; ri_ < 4; ++ri_) {
            const int rloc = 4 * myprow + ri_;
            if (r0 + rloc < OHW) {
                f32x16 acc0 = {0.f,0.f,0.f,0.f,0.f,0.f,0.f,0.f,0.f,0.f,0.f,0.f,0.f,0.f,0.f,0.f};
                f32x16 acc1 = {0.f,0.f,0.f,0.f,0.f,0.f,0.f,0.f,0.f,0.f,0.f,0.f,0.f,0.f,0.f,0.f};
                #pragma unroll
                for (int kk = 0; kk < 2; ++kk) {
                    const int arow = rloc + kk * 2 + h;   // dy-slot (3 -> zero wts, pad row)
                    #pragma unroll
                    for (int dx = 0; dx < 3; ++dx) {
                        short8v a = *(const short8v*)&Abuf[arow][colbase + dx][0];
                        acc0 = __builtin_amdgcn_mfma_f32_32x32x16_bf16(a, bq[dx][kk][0], acc0, 0, 0, 0);
                        acc1 = __builtin_amdgcn_mfma_f32_32x32x16_bf16(a, bq[dx][kk][1], acc1, 0, 0, 0);
                    }
                }
                const bool hi = (t32 == 3) && (h == 1);   // regs 14,15 = cols 126,127
                #pragma unroll
                for (int r = 0; r < 16; ++r) {
                    float a0 = acc0[r], a1 = acc1[r];
                    if (!(hi && r >= 14)) {
                        s1[0] += a0; s2[0] = fmaf(a0, a0, s2[0]);
                        s1[1] += a1; s2[1] = fmaf(a1, a1, s2[1]);
                    }
                    mzw[0][r >> 2] = fmaxf(mzw[0][r >> 2], a0);
                    mzw[1][r >> 2] = fmaxf(mzw[1][r >> 2], a1);
                }
            }
        }
        if (prow_g < PH) {
            #pragma unroll
            for (int q = 0; q < 4; ++q) {
                const int pc = 8 * t32 + 2 * q + h;
                if (pc < PH) {
                    float* dst = &mzbuf[((size_t)(b * PH + prow_g) * 32 + pc) * 64 + m31];
                    dst[0]  = mzw[0][q] + bsg[0];   // = max(sgn*(raw+bias)), ch = m31
                    dst[32] = mzw[1][q] + bsg[1];   // ch = 32+m31
                }
            }
        }
    }

    // post-loop bias/sign fixup, then reduce (r15 verbatim)
    #pragma unroll
    for (int nt = 0; nt < 2; ++nt) {
        float t1 = s1[nt] * sgn[nt];
        s2[nt] = fmaf(bs2[nt], t1, s2[nt]);
        s1[nt] = t1;
        s1[nt] += __shfl_xor(s1[nt], 32);
        s1[nt] += __shfl_xor(s1[nt], 1);  s1[nt] += __shfl_xor(s1[nt], 2);
        s2[nt] += __shfl_xor(s2[nt], 32);
        s2[nt] += __shfl_xor(s2[nt], 1);  s2[nt] += __shfl_xor(s2[nt], 2);
    }
    if (lane < 32 && (lane & 3) == 0) {
        red[wave][(m31 >> 2)][0]     = s1[0];
        red[wave][(m31 >> 2)][1]     = s2[0];
        red[wave][8 + (m31 >> 2)][0] = s1[1];
        red[wave][8 + (m31 >> 2)][1] = s2[1];
    }
    __syncthreads();
    if (tid < 32) {
        int grp = tid >> 1, which = tid & 1;
        float v = red[0][grp][which] + red[1][grp][which] + red[2][grp][which] + red[3][grp][which];
        part[(((size_t)b * STRIPS_A + strip) * NG + grp) * 2 + which] = v;
    }
}

// ---- merged finalize+affine (round-13/15 form, unchanged) ----
__global__ __launch_bounds__(256) void finalize_affine(
    const float* __restrict__ part, const float* __restrict__ gnw,
    const float* __restrict__ gnb, const float* __restrict__ scale,
    const float* __restrict__ bias, const float* __restrict__ mzbuf,
    float* __restrict__ out)
{
    __shared__ float sl[PH * 65];
    __shared__ float A2s[COUT], Bvs[COUT];
    const int ph = blockIdx.x, b = blockIdx.y;
    const int tid = threadIdx.x;

    if (tid < COUT) {
        const int c = tid, grp = c >> 2;
        float s1 = 0.f, s2 = 0.f;
        for (int s = 0; s < STRIPS_A; ++s) {
            const float* p = &part[(((size_t)b * STRIPS_A + s) * NG + grp) * 2];
            s1 += p[0]; s2 += p[1];
        }
        float sumb = 0.f, sumb2 = 0.f;
        #pragma unroll
        for (int ci = 0; ci < 4; ++ci) {
            float bc = bias[grp * 4 + ci];
            sumb += bc; sumb2 += bc * bc;
        }
        const float N1 = (float)(OHW * OHW);
        float S1 = s1 + N1 * sumb;
        float S2 = s2 + N1 * sumb2;
        const float invN = 1.f / (4.f * N1);
        float mean = S1 * invN;
        float var  = S2 * invN - mean * mean;
        float rstd = rsqrtf(var + GN_EPS);
        float gs = gnw[c] * scale[c];
        A2s[c] = rstd * fabsf(gs);
        Bvs[c] = (gnb[c] - mean * rstd * gnw[c]) * scale[c];
    }

    const float* src = mzbuf + (size_t)(b * PH + ph) * 32 * 64;
    for (int e = tid; e < PH * 64; e += 256) {
        int pc = e >> 6, c = e & 63;
        sl[pc * 65 + c] = src[pc * 64 + c];
    }
    __syncthreads();

    const int c = tid >> 2, q = tid & 3;
    const float A2 = A2s[c];
    const float B0 = Bvs[c];
    float* ob = out + (size_t)(b * COUT + c) * (PH * PH) + ph * PH;
    #pragma unroll
    for (int k = 0; k < 8; ++k) {
        int pw = q * 8 + k;
        if (pw < PH) {
            float v = fmaf(A2, sl[pw * 65 + c], B0);
            ob[pw] = fminf(fmaxf(v, 0.f), 1.f);
        }
    }
}

extern "C" void kernel_launch(void* const* d_in, const int* in_sizes, int n_in,
                              void* d_out, int out_size, void* d_ws, size_t ws_size,
                              hipStream_t stream)
{
    const float* x   = (const float*)d_in[0];
    const float* w   = (const float*)d_in[1];
    const float* cbv = (const float*)d_in[2];
    const float* gnw = (const float*)d_in[3];
    const float* gnb = (const float*)d_in[4];
    const float* sc  = (const float*)d_in[5];
    float* out = (float*)d_out;

    float* mzbuf = (float*)d_ws;                          // 128*31*32*64 f32 = 32.5 MB
    float* part  = mzbuf + (size_t)BATCH * PH * 32 * 64;  // 65536 f32

    conv_fused<<<dim3(STRIPS_A, BATCH), 256, 0, stream>>>(x, w, cbv, gnw, sc, part, mzbuf);
    finalize_affine<<<dim3(PH, BATCH), 256, 0, stream>>>(part, gnw, gnb, sc, cbv, mzbuf, out);
}

// Round 17
// 64.466 us; speedup vs baseline: 1.1421x; 1.1421x over previous
//
#include <hip/hip_runtime.h>

typedef __attribute__((ext_vector_type(8))) short short8v;
typedef __attribute__((ext_vector_type(16))) float f32x16;
typedef __attribute__((ext_vector_type(4))) int i32x4;

#define BATCH 128
#define CIN 8
#define HW 128
#define COUT 64
#define OHW 126
#define NG 16
#define PH 31
#define GN_EPS 1e-5f

#define ROWS_A 8
#define STRIPS_A 16
#define INROWS_A 11   // 10 real + 1 zero pad (kk=1,h=1 reads; zero weights there)
#define ACOLS 132

static __device__ __forceinline__ unsigned short f2bf(float f) {
    unsigned u = __float_as_uint(f);
    return (unsigned short)((u + 0x7fffu + ((u >> 16) & 1u)) >> 16);
}
static __device__ __forceinline__ unsigned pk2(float a, float b) {
    return (unsigned)f2bf(a) | ((unsigned)f2bf(b) << 16);
}

// ---- prep: pack weights * sgn into 32x32x16 B-fragment order, bf16 (r15 verbatim) ----
// frag f = dx*4 + kk*2 + nt; lane l: n = nt*32+(l&31), k=(l>>5)*8+j -> dy=kk*2+(l>>5), cin=j
__global__ __launch_bounds__(256) void prep_weights(
    const float* __restrict__ w, const float* __restrict__ gnw,
    const float* __restrict__ scale, short* __restrict__ Bpack)
{
    for (int e = threadIdx.x; e < 12 * 64; e += 256) {
        int f  = e >> 6;
        int l  = e & 63;
        int dx = f >> 2, kk = (f >> 1) & 1, nt = f & 1;
        int n  = nt * 32 + (l & 31);
        int dy = kk * 2 + (l >> 5);
        float sg = copysignf(1.f, gnw[n] * scale[n]);
        #pragma unroll
        for (int j = 0; j < 8; ++j) {
            float v = (dy < 3) ? w[((n * CIN + j) * 3 + dy) * 3 + dx] * sg : 0.f;
            Bpack[e * 8 + j] = (short)f2bf(v);
        }
    }
}

// ---- pass A (r15 verbatim, proven 43.5 µs): 32x32x16 bf16-MFMA conv ONCE:
//      stats + sign-folded pool maxes. ----
__global__ __launch_bounds__(256, 4) void conv_fused(
    const float* __restrict__ x, const short* __restrict__ Bpack,
    const float* __restrict__ bias, const float* __restrict__ gnw,
    const float* __restrict__ scale, float* __restrict__ part,
    float* __restrict__ mzbuf)
{
    __shared__ __align__(16) short Abuf[INROWS_A][ACOLS][8];
    __shared__ float red[4][NG][2];
    const int strip = blockIdx.x, b = blockIdx.y;
    const int tid = threadIdx.x, wave = tid >> 6, lane = tid & 63;
    const int h = lane >> 5, m31 = lane & 31;
    const int r0 = strip * ROWS_A;

    // B fragments into registers (12 x 16B)
    short8v bq[3][2][2];
    {
        const i32x4* bp = (const i32x4*)Bpack;
        #pragma unroll
        for (int dx = 0; dx < 3; ++dx)
            #pragma unroll
            for (int kk = 0; kk < 2; ++kk)
                #pragma unroll
                for (int nt = 0; nt < 2; ++nt) {
                    i32x4 v = bp[(dx * 4 + kk * 2 + nt) * 64 + lane];
                    bq[dx][kk][nt] = *(short8v*)&v;
                }
    }
    float sgn[2], bs2[2], bsg[2];
    #pragma unroll
    for (int nt = 0; nt < 2; ++nt) {
        int c = nt * 32 + m31;
        float bc = bias[c];
        float sg = copysignf(1.f, gnw[c] * scale[c]);
        sgn[nt] = sg;
        bs2[nt] = 2.f * bc;
        bsg[nt] = sg * bc;
    }

    // staging — round-2/11 verbatim
    {
        const float* xb = x + (size_t)b * CIN * HW * HW;
        for (int e = tid; e < INROWS_A * ACOLS; e += 256) {
            int row = e / ACOLS, col = e % ACOLS;
            int ri = r0 + row;
            bool ok = (row < 10) && (ri < HW) && (col < HW);
            unsigned pk0, pk1, pk2_, pk3;
            {
                const float* base = &xb[(size_t)ri * HW + col];
                float v0 = ok ? base[0 * HW * HW] : 0.f;
                float v1 = ok ? base[1 * HW * HW] : 0.f;
                float v2 = ok ? base[2 * HW * HW] : 0.f;
                float v3 = ok ? base[3 * HW * HW] : 0.f;
                float v4 = ok ? base[4 * HW * HW] : 0.f;
                float v5 = ok ? base[5 * HW * HW] : 0.f;
                float v6 = ok ? base[6 * HW * HW] : 0.f;
                float v7 = ok ? base[7 * HW * HW] : 0.f;
                pk0  = pk2(v0, v1);
                pk1  = pk2(v2, v3);
                pk2_ = pk2(v4, v5);
                pk3  = pk2(v6, v7);
            }
            uint4 w4 = make_uint4(pk0, pk1, pk2_, pk3);
            *(uint4*)&Abuf[row][col][0] = w4;
        }
    }
    __syncthreads();

    float s1[2] = {0.f, 0.f}, s2[2] = {0.f, 0.f};
    const int myprow = wave & 1;        // pool row within strip
    const int thalf  = wave >> 1;       // col-tile half
    const int prow_g = strip * 2 + myprow;

    for (int tt = 0; tt < 2; ++tt) {
        const int t32 = thalf * 2 + tt;           // 32-col tile 0..3
        const int colbase = 32 * t32 + m31;
        float mzw[2][4];
        #pragma unroll
        for (int nt = 0; nt < 2; ++nt)
            #pragma unroll
            for (int q = 0; q < 4; ++q) mzw[nt][q] = -3e38f;

        #pragma unroll
        for (int ri_ = 0; ri_ < 4; ++ri_) {
            const int rloc = 4 * myprow + ri_;
            if (r0 + rloc < OHW) {
                f32x16 acc0 = {0.f,0.f,0.f,0.f,0.f,0.f,0.f,0.f,0.f,0.f,0.f,0.f,0.f,0.f,0.f,0.f};
                f32x16 acc1 = {0.f,0.f,0.f,0.f,0.f,0.f,0.f,0.f,0.f,0.f,0.f,0.f,0.f,0.f,0.f,0.f};
                #pragma unroll
                for (int kk = 0; kk < 2; ++kk) {
                    const int arow = rloc + kk * 2 + h;   // dy-slot = kk*2+h (3 -> zero wts, pad row)
                    #pragma unroll
                    for (int dx = 0; dx < 3; ++dx) {
                        short8v a = *(const short8v*)&Abuf[arow][colbase + dx][0];
                        acc0 = __builtin_amdgcn_mfma_f32_32x32x16_bf16(a, bq[dx][kk][0], acc0, 0, 0, 0);
                        acc1 = __builtin_amdgcn_mfma_f32_32x32x16_bf16(a, bq[dx][kk][1], acc1, 0, 0, 0);
                    }
                }
                const bool hi = (t32 == 3) && (h == 1);   // regs 14,15 = cols 126,127
                #pragma unroll
                for (int r = 0; r < 16; ++r) {
                    float a0 = acc0[r], a1 = acc1[r];
                    if (!(hi && r >= 14)) {
                        s1[0] += a0; s2[0] = fmaf(a0, a0, s2[0]);
                        s1[1] += a1; s2[1] = fmaf(a1, a1, s2[1]);
                    }
                    mzw[0][r >> 2] = fmaxf(mzw[0][r >> 2], a0);
                    mzw[1][r >> 2] = fmaxf(mzw[1][r >> 2], a1);
                }
            }
        }
        if (prow_g < PH) {
            #pragma unroll
            for (int q = 0; q < 4; ++q) {
                const int pc = 8 * t32 + 2 * q + h;
                if (pc < PH) {
                    float* dst = &mzbuf[((size_t)(b * PH + prow_g) * 32 + pc) * 64 + m31];
                    dst[0]  = mzw[0][q] + bsg[0];   // = max(sgn*(raw+bias)), ch = m31
                    dst[32] = mzw[1][q] + bsg[1];   // ch = 32+m31
                }
            }
        }
    }

    // post-loop bias/sign fixup, then reduce: xor32 (col-halves) + xor1,2 (group quad)
    #pragma unroll
    for (int nt = 0; nt < 2; ++nt) {
        float t1 = s1[nt] * sgn[nt];
        s2[nt] = fmaf(bs2[nt], t1, s2[nt]);
        s1[nt] = t1;
        s1[nt] += __shfl_xor(s1[nt], 32);
        s1[nt] += __shfl_xor(s1[nt], 1);  s1[nt] += __shfl_xor(s1[nt], 2);
        s2[nt] += __shfl_xor(s2[nt], 32);
        s2[nt] += __shfl_xor(s2[nt], 1);  s2[nt] += __shfl_xor(s2[nt], 2);
    }
    if (lane < 32 && (lane & 3) == 0) {
        red[wave][(m31 >> 2)][0]     = s1[0];
        red[wave][(m31 >> 2)][1]     = s2[0];
        red[wave][8 + (m31 >> 2)][0] = s1[1];
        red[wave][8 + (m31 >> 2)][1] = s2[1];
    }
    __syncthreads();
    if (tid < 32) {
        int grp = tid >> 1, which = tid & 1;
        float v = red[0][grp][which] + red[1][grp][which] + red[2][grp][which] + red[3][grp][which];
        part[(((size_t)b * STRIPS_A + strip) * NG + grp) * 2 + which] = v;
    }
}

// ---- merged finalize+affine (round-13/15 form, unchanged) ----
__global__ __launch_bounds__(256) void finalize_affine(
    const float* __restrict__ part, const float* __restrict__ gnw,
    const float* __restrict__ gnb, const float* __restrict__ scale,
    const float* __restrict__ bias, const float* __restrict__ mzbuf,
    float* __restrict__ out)
{
    __shared__ float sl[PH * 65];
    __shared__ float A2s[COUT], Bvs[COUT];
    const int ph = blockIdx.x, b = blockIdx.y;
    const int tid = threadIdx.x;

    if (tid < COUT) {
        const int c = tid, grp = c >> 2;
        float s1 = 0.f, s2 = 0.f;
        for (int s = 0; s < STRIPS_A; ++s) {
            const float* p = &part[(((size_t)b * STRIPS_A + s) * NG + grp) * 2];
            s1 += p[0]; s2 += p[1];
        }
        float sumb = 0.f, sumb2 = 0.f;
        #pragma unroll
        for (int ci = 0; ci < 4; ++ci) {
            float bc = bias[grp * 4 + ci];
            sumb += bc; sumb2 += bc * bc;
        }
        const float N1 = (float)(OHW * OHW);
        float S1 = s1 + N1 * sumb;
        float S2 = s2 + N1 * sumb2;
        const float invN = 1.f / (4.f * N1);
        float mean = S1 * invN;
        float var  = S2 * invN - mean * mean;
        float rstd = rsqrtf(var + GN_EPS);
        float gs = gnw[c] * scale[c];
        A2s[c] = rstd * fabsf(gs);
        Bvs[c] = (gnb[c] - mean * rstd * gnw[c]) * scale[c];
    }

    const float* src = mzbuf + (size_t)(b * PH + ph) * 32 * 64;
    for (int e = tid; e < PH * 64; e += 256) {
        int pc = e >> 6, c = e & 63;
        sl[pc * 65 + c] = src[pc * 64 + c];
    }
    __syncthreads();

    const int c = tid >> 2, q = tid & 3;
    const float A2 = A2s[c];
    const float B0 = Bvs[c];
    float* ob = out + (size_t)(b * COUT + c) * (PH * PH) + ph * PH;
    #pragma unroll
    for (int k = 0; k < 8; ++k) {
        int pw = q * 8 + k;
        if (pw < PH) {
            float v = fmaf(A2, sl[pw * 65 + c], B0);
            ob[pw] = fminf(fmaxf(v, 0.f), 1.f);
        }
    }
}

extern "C" void kernel_launch(void* const* d_in, const int* in_sizes, int n_in,
                              void* d_out, int out_size, void* d_ws, size_t ws_size,
                              hipStream_t stream)
{
    const float* x   = (const float*)d_in[0];
    const float* w   = (const float*)d_in[1];
    const float* cbv = (const float*)d_in[2];
    const float* gnw = (const float*)d_in[3];
    const float* gnb = (const float*)d_in[4];
    const float* sc  = (const float*)d_in[5];
    float* out = (float*)d_out;

    float* mzbuf = (float*)d_ws;                          // 128*31*32*64 f32 = 32.5 MB
    float* part  = mzbuf + (size_t)BATCH * PH * 32 * 64;  // 65536 f32
    short* Bpack = (short*)(part + 65536);                // 6144 bf16

    prep_weights<<<dim3(1), 256, 0, stream>>>(w, gnw, sc, Bpack);
    conv_fused<<<dim3(STRIPS_A, BATCH), 256, 0, stream>>>(x, Bpack, cbv, gnw, sc, part, mzbuf);
    finalize_affine<<<dim3(PH, BATCH), 256, 0, stream>>>(part, gnw, gnb, sc, cbv, mzbuf, out);
}